// Round 7
// baseline (465.705 us; speedup 1.0000x reference)
//
#include <hip/hip_runtime.h>
#include <cmath>

// ---------------- problem constants ----------------
#define NLAYERS 100      // hidden layers (scan)
#define DIN     64       // input features
#define WDIM    100      // hidden width
#define NPAD    112      // padded N (7 tiles of 16)
#define NT      7        // n tiles
#define RT      2        // row tiles -> 32 batch rows/wave; W-frags shared across both
#define ROWS    32
#define PSTR    136      // f16 plane row stride (272 B: b128-aligned, pad cols 112..127)
#define PLANE   (16 * PSTR)   // one plane (one row-tile, one of hi/lo) in halves

typedef _Float16 half8 __attribute__((ext_vector_type(8)));
typedef __fp16   fp16x2 __attribute__((ext_vector_type(2)));   // cvt_pkrtz return type
typedef float    f32x4 __attribute__((ext_vector_type(4)));

// ---------------- workspace layout ----------------
#define WSH_LAYER_HALVES (NT * 4 * 64 * 8)               // 14336 halves per hidden layer
#define WSH_HALVES       (NLAYERS * WSH_LAYER_HALVES)    // 1,433,600
#define W0_HALVES        (NT * 2 * 64 * 8)               // 7168 (input layer, K=64)
#define BPAD_FLOATS      ((NLAYERS + 1) * NPAD)          // 11312 (row 0 = b_in acc init)
#define OFF_BPAD_B       ((WSH_HALVES + W0_HALVES) * 2)  // bytes, 16-aligned
#define OFF_WOUT_B       (OFF_BPAD_B + BPAD_FLOATS * 4)  // bytes, 16-aligned
#define TOTAL_PREP       (WSH_HALVES + W0_HALVES + BPAD_FLOATS + NPAD)

// ============================================================
// Prep: shuffle weights into MFMA A-operand order (f16), operand-swapped:
// frag (nt,ks), lane(q,l15), elem j holds W[k=ks*32+q*8+j][n=nt*16+l15].
// Row k==112 of each hidden-layer fragment = layer bias (h col 112 == 1.0).
// ============================================================
__global__ void actor_prep(const float* __restrict__ Win, const float* __restrict__ bin,
                           const float* __restrict__ Ws,  const float* __restrict__ bs,
                           const float* __restrict__ Wout,
                           _Float16* __restrict__ wsh, _Float16* __restrict__ w0sh,
                           float* __restrict__ bpad, float* __restrict__ woutp) {
    int t = blockIdx.x * 256 + threadIdx.x;
    if (t < WSH_HALVES) {                       // hidden-layer weights (+ bias row at k=112)
        int j    = t & 7;
        int lane = (t >> 3) & 63;
        int ks   = (t >> 9) & 3;
        int rest = t >> 11;                     // l*7 + nt
        int nt   = rest % 7;
        int l    = rest / 7;
        int qq = lane >> 4, ll = lane & 15;
        int k = ks * 32 + qq * 8 + j;
        int n = nt * 16 + ll;
        float v = 0.f;
        if (k < WDIM && n < WDIM)       v = Ws[(l * WDIM + k) * WDIM + n];
        else if (k == 112 && n < WDIM)  v = bs[l * WDIM + n];   // bias row
        wsh[t] = (_Float16)v;
        return;
    }
    int t2 = t - WSH_HALVES;
    if (t2 < W0_HALVES) {                       // input layer weights (K=64, bias via acc init)
        int j    = t2 & 7;
        int lane = (t2 >> 3) & 63;
        int ks   = (t2 >> 9) & 1;
        int nt   = t2 >> 10;
        int qq = lane >> 4, ll = lane & 15;
        int k = ks * 32 + qq * 8 + j;
        int n = nt * 16 + ll;
        float v = (k < DIN && n < WDIM) ? Win[k * WDIM + n] : 0.f;
        w0sh[t2] = (_Float16)v;
        return;
    }
    int t3 = t2 - W0_HALVES;
    if (t3 < BPAD_FLOATS) {                     // padded biases: row 0 = b_in
        int l = t3 / NPAD, c = t3 % NPAD;
        float v = 0.f;
        if (c < WDIM) v = (l == 0) ? bin[c] : bs[(l - 1) * WDIM + c];
        bpad[t3] = v;
        return;
    }
    int t4 = t3 - BPAD_FLOATS;
    if (t4 < NPAD) woutp[t4] = (t4 < WDIM) ? Wout[t4] : 0.f;
}

// split fp32 -> hi/lo fp16 (layer-0 input only)
__device__ __forceinline__ void split8(const float* __restrict__ p, half8& hi, half8& lo) {
    f32x4 u0 = *(const f32x4*)p;
    f32x4 u1 = *(const f32x4*)(p + 4);
    float v[8] = {u0[0], u0[1], u0[2], u0[3], u1[0], u1[1], u1[2], u1[3]};
#pragma unroll
    for (int e = 0; e < 8; e += 2) {
        fp16x2 h = __builtin_amdgcn_cvt_pkrtz(v[e], v[e + 1]);
        float r0 = v[e]     - (float)h[0];
        float r1 = v[e + 1] - (float)h[1];
        fp16x2 l = __builtin_amdgcn_cvt_pkrtz(r0, r1);
        hi[e] = (_Float16)h[0]; hi[e + 1] = (_Float16)h[1];
        lo[e] = (_Float16)l[0]; lo[e + 1] = (_Float16)l[1];
    }
}

// epilogue one C-tile: leaky + hi/lo split + 2x ds_write_b64
__device__ __forceinline__ void ep_tile(const f32x4 a, _Float16* hA, _Float16* hB, int idx) {
    float v0 = fmaxf(a[0], 0.01f * a[0]);
    float v1 = fmaxf(a[1], 0.01f * a[1]);
    float v2 = fmaxf(a[2], 0.01f * a[2]);
    float v3 = fmaxf(a[3], 0.01f * a[3]);
    fp16x2 h01 = __builtin_amdgcn_cvt_pkrtz(v0, v1);
    fp16x2 h23 = __builtin_amdgcn_cvt_pkrtz(v2, v3);
    fp16x2 l01 = __builtin_amdgcn_cvt_pkrtz(v0 - (float)h01[0], v1 - (float)h01[1]);
    fp16x2 l23 = __builtin_amdgcn_cvt_pkrtz(v2 - (float)h23[0], v3 - (float)h23[1]);
    uint2 hw; hw.x = __builtin_bit_cast(unsigned, h01); hw.y = __builtin_bit_cast(unsigned, h23);
    uint2 lw; lw.x = __builtin_bit_cast(unsigned, l01); lw.y = __builtin_bit_cast(unsigned, l23);
    *reinterpret_cast<uint2*>(hA + idx) = hw;
    *reinterpret_cast<uint2*>(hB + idx) = lw;
}

// ============================================================
// One hidden layer, software-pipelined: accumulate C (this layer) while
// draining P (prev layer's accs) JUST-IN-TIME — col group nt of h(prev)
// is written right before the ks = nt/2 step that reads it:
//   boundary: nt 0,1  |  during ks0: nt 2,3  |  ks1: nt 4,5  |  ks2: nt 6
// Epilogue VALU/DS-writes are independent of the 28-MFMA blocks around
// them -> scheduler hides them in the MFMA shadow. Bias rides W row 112.
// ============================================================
__device__ __forceinline__ void hidden_layer(
    f32x4 (&C)[RT][NT], f32x4 (&P)[RT][NT], half8 (&wb)[2][NT],
    const _Float16* __restrict__ wl, const _Float16* __restrict__ wlnext,
    _Float16* hp, const int lane, const int q, const int l15)
{
    const int colbase = l15 * PSTR;
    const f32x4 zero4 = {0.f, 0.f, 0.f, 0.f};

    // boundary: h(prev) cols 0..31 (nt=0,1), needed by ks0
#pragma unroll
    for (int rt = 0; rt < RT; ++rt) {
        _Float16* hA = hp + (rt * 2 + 0) * PLANE;
        _Float16* hB = hp + (rt * 2 + 1) * PLANE;
        ep_tile(P[rt][0], hA, hB, colbase + 0 * 16 + q * 4);
        ep_tile(P[rt][1], hA, hB, colbase + 1 * 16 + q * 4);
    }
#pragma unroll
    for (int rt = 0; rt < RT; ++rt)
#pragma unroll
        for (int nt = 0; nt < NT; ++nt) C[rt][nt] = zero4;   // bias via k=112 row

#pragma unroll
    for (int ks = 0; ks < 4; ++ks) {
        const int cur = ks & 1, nxt = cur ^ 1;
        // prefetch next k-step (or next layer's ks=0) W frags — shared by both row-tiles
        const _Float16* src = (ks < 3) ? (wl + ((ks + 1) * 64 + lane) * 8)
                                       : (wlnext + lane * 8);
#pragma unroll
        for (int nt = 0; nt < NT; ++nt)
            wb[nxt][nt] = *(const half8*)(src + nt * 4 * 64 * 8);

#pragma unroll
        for (int rt = 0; rt < RT; ++rt) {
            half8 bhi = *(const half8*)(hp + (rt * 2 + 0) * PLANE + colbase + ks * 32 + q * 8);
#pragma unroll
            for (int nt = 0; nt < NT; ++nt)
                C[rt][nt] = __builtin_amdgcn_mfma_f32_16x16x32_f16(wb[cur][nt], bhi, C[rt][nt], 0, 0, 0);
        }
        if (ks < 3) {
#pragma unroll
            for (int rt = 0; rt < RT; ++rt) {
                half8 blo = *(const half8*)(hp + (rt * 2 + 1) * PLANE + colbase + ks * 32 + q * 8);
#pragma unroll
                for (int nt = 0; nt < NT; ++nt)
                    C[rt][nt] = __builtin_amdgcn_mfma_f32_16x16x32_f16(wb[cur][nt], blo, C[rt][nt], 0, 0, 0);
            }
            // JIT drain of P for the NEXT ks step's columns
            const int nt0 = 2 * (ks + 1);
#pragma unroll
            for (int rt = 0; rt < RT; ++rt) {
                _Float16* hA = hp + (rt * 2 + 0) * PLANE;
                _Float16* hB = hp + (rt * 2 + 1) * PLANE;
                ep_tile(P[rt][nt0], hA, hB, colbase + nt0 * 16 + q * 4);
                if (nt0 + 1 < NT)
                    ep_tile(P[rt][nt0 + 1], hA, hB, colbase + (nt0 + 1) * 16 + q * 4);
            }
        }
    }
}

// ============================================================
// Main: one wave/block, 32 batch rows, fully fused, ping-pong acc sets
// (X/Y) so each layer drains the previous layer's accs inside its own
// MFMA stream. Head computed directly from final fp32 accs (no LDS trip).
// ============================================================
__global__ __launch_bounds__(64, 2)
void actor_main(const float* __restrict__ x,
                const _Float16* __restrict__ wsh,
                const _Float16* __restrict__ w0sh,
                const float* __restrict__ bpad,
                const float* __restrict__ woutp,
                const float* __restrict__ bout,
                float* __restrict__ out) {
    __shared__ _Float16 hp[2 * 2 * PLANE];   // [rt][plane]; plane0=hi, plane1=lo
    const int lane = threadIdx.x;
    const int q = lane >> 4, l15 = lane & 15;
    const int rowbase = blockIdx.x * ROWS;

    f32x4 accX[RT][NT], accY[RT][NT];
    half8 wb[2][NT];

    // ---- one-time pad init: cols 112..127 zero in all 4 planes, hi[.,112]=1.0 ----
    {
        const int pl = lane >> 4, row = lane & 15;    // pl in [0,4)
        const half8 z = {0, 0, 0, 0, 0, 0, 0, 0};
        *(half8*)(hp + pl * PLANE + row * PSTR + 112) = z;
        *(half8*)(hp + pl * PLANE + row * PSTR + 120) = z;
        if (lane < 32) {
            const int rt = lane >> 4, r = lane & 15;
            hp[(rt * 2 + 0) * PLANE + r * PSTR + 112] = (_Float16)1.0f;  // bias multiplier
        }
    }

    // preload input-layer ks=0 W frags; accX init = b_in
#pragma unroll
    for (int nt = 0; nt < NT; ++nt) {
        wb[0][nt] = *(const half8*)(w0sh + ((nt * 2 + 0) * 64 + lane) * 8);
        f32x4 b = *(const f32x4*)(bpad + nt * 16 + q * 4);
        accX[0][nt] = b;
        accX[1][nt] = b;
    }

    // ---------------- layer 0: x @ W_in (K=64) -> accX ----------------
#pragma unroll
    for (int ks = 0; ks < 2; ++ks) {
        const int cur = ks & 1, nxt = cur ^ 1;
        if (ks == 0) {
#pragma unroll
            for (int nt = 0; nt < NT; ++nt)
                wb[nxt][nt] = *(const half8*)(w0sh + ((nt * 2 + 1) * 64 + lane) * 8);
        } else {          // prefetch hidden layer 0, ks=0 -> wb[0] (invariant)
#pragma unroll
            for (int nt = 0; nt < NT; ++nt)
                wb[nxt][nt] = *(const half8*)(wsh + (lane) * 8 + nt * 4 * 64 * 8);
        }
#pragma unroll
        for (int rt = 0; rt < RT; ++rt) {
            half8 xhi, xlo;
            split8(x + (rowbase + rt * 16 + l15) * DIN + ks * 32 + q * 8, xhi, xlo);
#pragma unroll
            for (int nt = 0; nt < NT; ++nt) {
                accX[rt][nt] = __builtin_amdgcn_mfma_f32_16x16x32_f16(wb[cur][nt], xhi, accX[rt][nt], 0, 0, 0);
                accX[rt][nt] = __builtin_amdgcn_mfma_f32_16x16x32_f16(wb[cur][nt], xlo, accX[rt][nt], 0, 0, 0);
            }
        }
    }

    // ---------------- 100 hidden layers: 50 ping-pong pairs ----------------
#pragma unroll 1
    for (int l = 0; l < NLAYERS; l += 2) {
        const _Float16* w0l = wsh + l * WSH_LAYER_HALVES;
        const _Float16* w1l = wsh + (l + 1) * WSH_LAYER_HALVES;
        const _Float16* w2l = (l + 2 < NLAYERS) ? (wsh + (l + 2) * WSH_LAYER_HALVES) : w1l;
        hidden_layer(accY, accX, wb, w0l, w1l, hp, lane, q, l15);  // drain X, acc Y
        hidden_layer(accX, accY, wb, w1l, w2l, hp, lane, q, l15);  // drain Y, acc X
    }
    // final pre-activations in accX

    // ---------------- head: leaky + dot(W_out) from regs, reduce over q ----------------
#pragma unroll
    for (int rt = 0; rt < RT; ++rt) {
        float s = 0.f;
#pragma unroll
        for (int nt = 0; nt < NT; ++nt) {
            f32x4 w4 = *(const f32x4*)(woutp + nt * 16 + q * 4);
#pragma unroll
            for (int r = 0; r < 4; ++r) {
                float a = accX[rt][nt][r];
                float v = fmaxf(a, 0.01f * a);
                s += v * w4[r];
            }
        }
        s += __shfl_xor(s, 16);   // sum across q pairs
        s += __shfl_xor(s, 32);
        if (q == 0) {
            float aa = s + bout[0];
            float t = tanhf(aa);
            out[rowbase + rt * 16 + l15] = t * 4.5f + 5.5f;   // (tanh+1)/2*9 + 1
        }
    }
}

extern "C" void kernel_launch(void* const* d_in, const int* in_sizes, int n_in,
                              void* d_out, int out_size, void* d_ws, size_t ws_size,
                              hipStream_t stream) {
    const float* x    = (const float*)d_in[0];
    const float* Win  = (const float*)d_in[1];
    const float* bin  = (const float*)d_in[2];
    const float* Ws   = (const float*)d_in[3];
    const float* bs   = (const float*)d_in[4];
    const float* Wout = (const float*)d_in[5];
    const float* bout = (const float*)d_in[6];
    float* out = (float*)d_out;

    char* ws = (char*)d_ws;
    _Float16* wsh  = (_Float16*)ws;
    _Float16* w0sh = wsh + WSH_HALVES;
    float* bpad  = (float*)(ws + OFF_BPAD_B);
    float* woutp = (float*)(ws + OFF_WOUT_B);

    hipLaunchKernelGGL(actor_prep, dim3((TOTAL_PREP + 255) / 256), dim3(256), 0, stream,
                       Win, bin, Ws, bs, Wout, wsh, w0sh, bpad, woutp);

    const int nrows = in_sizes[0] / DIN;   // 65536
    hipLaunchKernelGGL(actor_main, dim3(nrows / ROWS), dim3(64), 0, stream,
                       x, wsh, w0sh, bpad, woutp, bout, out);
}